// Round 15
// baseline (256.421 us; speedup 1.0000x reference)
//
#include <hip/hip_runtime.h>
#include <math.h>

typedef __attribute__((ext_vector_type(8))) short short8;
typedef __attribute__((ext_vector_type(4))) float floatx4;

__device__ __forceinline__ unsigned short f2bf(float f) {
    union { float f; unsigned u; } v; v.f = f;
    unsigned r = v.u + 0x7fffu + ((v.u >> 16) & 1u);
    return (unsigned short)(r >> 16);
}

// truncating f32->bf16 (1 VALU op); P-staging only (error << threshold)
__device__ __forceinline__ unsigned short f2bf_t(float f) {
    union { float f; unsigned u; } v; v.f = f;
    return (unsigned short)(v.u >> 16);
}

__device__ __forceinline__ float bf2f(unsigned short h) {
    union { unsigned u; float f; } v; v.u = ((unsigned)h) << 16; return v.f;
}

__device__ __forceinline__ float fexp2(float x) {
#if __has_builtin(__builtin_amdgcn_exp2f)
    return __builtin_amdgcn_exp2f(x);
#else
    return __expf(x * 0.69314718056f);
#endif
}

// async global->LDS, 16B per lane; lds base must be wave-uniform (HW adds lane*16)
__device__ __forceinline__ void gload16(const unsigned short* g, unsigned short* l) {
    __builtin_amdgcn_global_load_lds(
        (const __attribute__((address_space(1))) unsigned int*)g,
        (__attribute__((address_space(3))) unsigned int*)l, 16, 0, 0);
}

#define VMC(n) asm volatile("s_waitcnt vmcnt(" #n ")" ::: "memory")

// ---------------- LayerNorm (fp32 in -> bf16 out), one block per row of 768 ----
__global__ __launch_bounds__(256) void ln_kernel(const float* __restrict__ x,
                                                 const float* __restrict__ w,
                                                 const float* __restrict__ b,
                                                 unsigned short* __restrict__ o) {
    int row = blockIdx.x, tid = threadIdx.x;
    const float* xr = x + (size_t)row * 768;
    float v0 = xr[tid], v1 = xr[tid + 256], v2 = xr[tid + 512];
    float s = v0 + v1 + v2, ss = v0 * v0 + v1 * v1 + v2 * v2;
#pragma unroll
    for (int o_ = 32; o_; o_ >>= 1) { s += __shfl_xor(s, o_); ss += __shfl_xor(ss, o_); }
    __shared__ float red[8];
    if ((tid & 63) == 0) { red[tid >> 6] = s; red[(tid >> 6) + 4] = ss; }
    __syncthreads();
    s = red[0] + red[1] + red[2] + red[3];
    ss = red[4] + red[5] + red[6] + red[7];
    float mu = s * (1.f / 768.f);
    float var = ss * (1.f / 768.f) - mu * mu;
    float inv = rsqrtf(var + 1e-5f);
    unsigned short* orow = o + (size_t)row * 768;
    orow[tid]       = f2bf((v0 - mu) * inv * w[tid]       + b[tid]);
    orow[tid + 256] = f2bf((v1 - mu) * inv * w[tid + 256] + b[tid + 256]);
    orow[tid + 512] = f2bf((v2 - mu) * inv * w[tid + 512] + b[tid + 512]);
}

// ------- All 4 weight converts fused: fp32 [K,N] -> bf16 transposed [N,K] -----
__global__ __launch_bounds__(256) void wt_all_kernel(
    const float* __restrict__ w0, unsigned short* __restrict__ t0,
    const float* __restrict__ w1, unsigned short* __restrict__ t1,
    const float* __restrict__ w2, unsigned short* __restrict__ t2,
    const float* __restrict__ w3, unsigned short* __restrict__ t3) {
    int bid = (int)blockIdx.x;
    const float* w; unsigned short* wt; int K, N, bx, by;
    if (bid < 1728)      { w = w0; wt = t0; K = 768;  N = 2304; int l = bid;        bx = l % 72; by = l / 72; }
    else if (bid < 2304) { w = w1; wt = t1; K = 768;  N = 768;  int l = bid - 1728; bx = l % 24; by = l / 24; }
    else if (bid < 4608) { w = w2; wt = t2; K = 768;  N = 3072; int l = bid - 2304; bx = l % 96; by = l / 96; }
    else                 { w = w3; wt = t3; K = 3072; N = 768;  int l = bid - 4608; bx = l % 24; by = l / 24; }
    __shared__ float t[32][33];
    int n0 = bx * 32, k0 = by * 32;
    int tx = threadIdx.x & 31, ty = threadIdx.x >> 5;
#pragma unroll
    for (int i = 0; i < 32; i += 8)
        t[ty + i][tx] = w[(size_t)(k0 + ty + i) * N + n0 + tx];
    __syncthreads();
#pragma unroll
    for (int i = 0; i < 32; i += 8)
        wt[(size_t)(n0 + ty + i) * K + k0 + tx] = f2bf(t[tx][ty + i]);
}

// ---------------- GEMM: C[M,N] = A[M,K](bf16) @ Bt[N,K](bf16)^T, epilogues -----
// Depth-4 staging ring with COUNTED vmcnt (no sched_barrier, no vmcnt(0) drain
// in steady state): stage(t) waited via vmcnt(8) while stages t+1,t+2 stay in
// flight (~3 iterations of slack >= HBM latency). XCD-chunked swizzle.
// EPI 0: qkv split; EPI 1: +bias+resid fp32; EPI 2: gelu; EPI 4: split-K partial.
template <int EPI>
__global__ __launch_bounds__(256) void gemm_kernel(
    const unsigned short* __restrict__ A, const unsigned short* __restrict__ Bt,
    const float* __restrict__ bias, const float* __restrict__ resid,
    float* __restrict__ fout, unsigned short* __restrict__ o0,
    unsigned short* __restrict__ o1, unsigned short* __restrict__ o2,
    int K, int Kcnt) {
    __shared__ unsigned short Al[4][128 * 32];
    __shared__ unsigned short Bl[4][128 * 32];
    int tid = threadIdx.x, lane = tid & 63, w = tid >> 6;
    int wm = w >> 1, wn = w & 1;
    int nwg = (int)(gridDim.x * gridDim.y);
    int wgid = (int)(blockIdx.y * gridDim.x + blockIdx.x);
    int logical = (wgid & 7) * (nwg >> 3) + (wgid >> 3);
    int by = logical & 31, bx = logical >> 5;
    int m0 = by * 128;
    int n0, kof = 0, chunk = 0;
    if (EPI == 4) {
        n0 = (bx % 6) * 128;
        chunk = bx / 6;
        kof = chunk * Kcnt;
    } else {
        n0 = bx * 128;
    }
    int lr = lane & 15, lk = (lane >> 4) << 3;

    int srow = w * 32 + (lane >> 2);
    int sko = (lane & 3) << 3;
    const unsigned short* Ab = A + (size_t)(m0 + srow) * K + kof + sko;
    const unsigned short* Bb = Bt + (size_t)(n0 + srow) * K + kof + sko;

    floatx4 acc[4][4];
#pragma unroll
    for (int i = 0; i < 4; i++)
#pragma unroll
        for (int j = 0; j < 4; j++) acc[i][j] = (floatx4){0.f, 0.f, 0.f, 0.f};

    int nk = Kcnt >> 5;
    auto stage = [&](int buf, int t) {
        int k0 = t << 5;
        unsigned short* Alp = &Al[buf][(w * 32) * 32];
        unsigned short* Blp = &Bl[buf][(w * 32) * 32];
        gload16(Ab + k0, Alp);
        gload16(Ab + 16 * K + k0, Alp + 16 * 32);
        gload16(Bb + k0, Blp);
        gload16(Bb + 16 * K + k0, Blp + 16 * 32);
    };

    // prologue: 3 stages in flight
    stage(0, 0);
    if (nk > 1) stage(1, 1);
    if (nk > 2) stage(2, 2);
    for (int t = 0; t < nk; t++) {
        int cur = t & 3;
        int rem = nk - t;
        // wait for stage(t) only; stages t+1,t+2 (8 instrs/wave) stay in flight
        if (rem > 2)       VMC(8);
        else if (rem == 2) VMC(4);
        else               VMC(0);
        __builtin_amdgcn_s_barrier();   // publish all waves' DMA for buf[cur]
        if (t + 3 < nk) stage((t + 3) & 3, t + 3);   // ~3 iterations to land
        short8 af[4], bfr[4];
#pragma unroll
        for (int mt = 0; mt < 4; mt++) af[mt] = *(short8*)&Al[cur][(wm * 64 + mt * 16 + lr) * 32 + lk];
#pragma unroll
        for (int nt = 0; nt < 4; nt++) bfr[nt] = *(short8*)&Bl[cur][(wn * 64 + nt * 16 + lr) * 32 + lk];
#pragma unroll
        for (int mt = 0; mt < 4; mt++)
#pragma unroll
            for (int nt = 0; nt < 4; nt++)
                acc[mt][nt] = __builtin_amdgcn_mfma_f32_16x16x32_bf16(af[mt], bfr[nt], acc[mt][nt], 0, 0, 0);
    }

    int mb = m0 + wm * 64, nb = n0 + wn * 64;
    int sec = 0;
    if (EPI == 0) sec = n0 / 768;
#pragma unroll
    for (int mt = 0; mt < 4; mt++)
#pragma unroll
        for (int nt = 0; nt < 4; nt++)
#pragma unroll
            for (int r = 0; r < 4; r++) {
                int mrow = mb + mt * 16 + ((lane >> 4) << 2) + r;
                int ncol = nb + nt * 16 + lr;
                float val = acc[mt][nt][r];
                if (EPI != 4) val += bias[ncol];
                if (EPI == 0) {
                    int f = ncol - sec * 768;
                    int h = f >> 6, d = f & 63;
                    int bb = mrow >> 11, t = mrow & 2047;
                    if (sec == 0)
                        o0[((size_t)(bb * 12 + h) * 2048 + t) * 64 + d] = f2bf(val * 0.1803368801f);
                    else if (sec == 1)
                        o1[((size_t)(bb * 12 + h) * 2048 + t) * 64 + d] = f2bf(val);
                    else
                        o2[((size_t)(bb * 12 + h) * 64 + d) * 2048 + t] = f2bf(val);
                } else if (EPI == 1) {
                    fout[(size_t)mrow * 768 + ncol] = val + resid[(size_t)mrow * 768 + ncol];
                } else if (EPI == 2) {
                    float g = 0.5f * val * (1.f + erff(val * 0.70710678118f));
                    o0[(size_t)mrow * 3072 + ncol] = f2bf(g);
                } else if (EPI == 4) {
                    unsigned short* op = (chunk == 0) ? o0 : (chunk == 1) ? o1
                                       : (chunk == 2) ? o2 : (unsigned short*)fout;
                    op[(size_t)mrow * 768 + ncol] = f2bf(val);
                }
            }
}

// -------- split-K combine: out = p0+p1+p2+p3 + bias + resid (fp32), N=768 -----
__global__ __launch_bounds__(256) void sk_combine(
    const unsigned short* __restrict__ p0, const unsigned short* __restrict__ p1,
    const unsigned short* __restrict__ p2, const unsigned short* __restrict__ p3,
    const float* __restrict__ bias, const float* __restrict__ resid,
    float* __restrict__ out) {
    int i = blockIdx.x * 256 + threadIdx.x;
    size_t base = (size_t)i * 8;
    int col = (int)(base % 768);
    short8 a0 = *(const short8*)&p0[base];
    short8 a1 = *(const short8*)&p1[base];
    short8 a2 = *(const short8*)&p2[base];
    short8 a3 = *(const short8*)&p3[base];
#pragma unroll
    for (int j = 0; j < 8; j++) {
        float s = bf2f((unsigned short)a0[j]) + bf2f((unsigned short)a1[j]) +
                  bf2f((unsigned short)a2[j]) + bf2f((unsigned short)a3[j]);
        out[base + j] = s + bias[col + j] + resid[base + j];
    }
}

// ---------------- Flash attention (causal), split-KV across blocks ------------
// Block = (bq, c): q-rows [bq*128, +128), KV tiles [c*8, min(c*8+8, 2bq+2)).
// K staged in LDS (XOR-swizzled dbuf gload_lds); V direct from global, issued
// BEFORE stage(t+1) so PV's compiler wait leaves the K-prefetch in flight.
__global__ __launch_bounds__(256) void attn_kernel(const unsigned short* __restrict__ q_s,
                                                   const unsigned short* __restrict__ k_s,
                                                   const unsigned short* __restrict__ v_t,
                                                   unsigned short* __restrict__ y,
                                                   unsigned short* __restrict__ opart,
                                                   float* __restrict__ lpart) {
    __shared__ unsigned short KVs[2][4096];
    __shared__ unsigned short Pls[4][32][72];
    const int T = 2048, H = 12;
    int tid = threadIdx.x, lane = tid & 63, w = tid >> 6;
    int xx = (int)blockIdx.x;
    int bq, c;
    if (xx < 16)      { c = 0; bq = xx; }
    else if (xx < 28) { c = 1; bq = xx - 12; }
    else if (xx < 36) { c = 2; bq = xx - 20; }
    else              { c = 3; bq = xx - 24; }
    int bh = blockIdx.y;
    int bi = bh / H, hh = bh - bi * H;
    const unsigned short* qp = q_s + (size_t)bh * T * 64;
    const unsigned short* kp = k_s + (size_t)bh * T * 64;
    const unsigned short* vp = v_t + (size_t)bh * 64 * T;
    int wq0 = bq * 128 + w * 32;
    int lr = lane & 15, lk8 = (lane >> 4) << 3, hi = lane >> 4;
    int nt_blk = 2 * bq + 2;
    int t0 = c * 8;
    int t1 = t0 + 8 < nt_blk ? t0 + 8 : nt_blk;

    unsigned short (*Pl)[72] = Pls[w];
    int srow = tid >> 3, ssl = tid & 7;

    auto stage = [&](int buf, int t) {
        int kv0 = t * 64;
        unsigned short* base = &KVs[buf][(tid >> 6) * 512];
#pragma unroll
        for (int h = 0; h < 2; h++) {
            int r = srow + h * 32;
            int ss = ssl ^ (r & 7);
            gload16(kp + (size_t)(kv0 + r) * 64 + ss * 8, base + h * 2048);
        }
    };

    short8 aq[2][2];
#pragma unroll
    for (int mt = 0; mt < 2; mt++)
#pragma unroll
        for (int kf = 0; kf < 2; kf++)
            aq[mt][kf] = *(const short8*)&qp[(size_t)(wq0 + mt * 16 + lr) * 64 + kf * 32 + lk8];

    floatx4 yacc[2][4];
    float lacc[2][4];
#pragma unroll
    for (int i = 0; i < 2; i++)
#pragma unroll
        for (int j = 0; j < 4; j++) {
            yacc[i][j] = (floatx4){0.f, 0.f, 0.f, 0.f};
            lacc[i][j] = 0.f;
        }

    stage(0, t0);
    __syncthreads();

    for (int t = t0; t < t1; t++) {
        int cur = (t - t0) & 1;
        int kv0 = t * 64;
        bool live = (kv0 <= wq0 + 31);
        // V direct from global, issued FIRST (oldest in vmcnt queue)
        short8 bv[4][2];
        if (live) {
#pragma unroll
            for (int nt = 0; nt < 4; nt++)
#pragma unroll
                for (int kf = 0; kf < 2; kf++)
                    bv[nt][kf] = *(const short8*)&vp[(size_t)(nt * 16 + lr) * T + kv0 + kf * 32 + lk8];
        }
        if (t + 1 < t1) stage(cur ^ 1, t + 1);
        if (live) {
            const unsigned short* Kt = &KVs[cur][0];
            floatx4 sacc[2][4];
#pragma unroll
            for (int i = 0; i < 2; i++)
#pragma unroll
                for (int j = 0; j < 4; j++) sacc[i][j] = (floatx4){0.f, 0.f, 0.f, 0.f};
#pragma unroll
            for (int kf = 0; kf < 2; kf++) {
                int sl = ((kf << 2) | hi) ^ (lr & 7);
                short8 bk[4];
#pragma unroll
                for (int nt = 0; nt < 4; nt++)
                    bk[nt] = *(const short8*)&Kt[(nt * 16 + lr) * 64 + sl * 8];
#pragma unroll
                for (int mt = 0; mt < 2; mt++)
#pragma unroll
                    for (int nt = 0; nt < 4; nt++)
                        sacc[mt][nt] = __builtin_amdgcn_mfma_f32_16x16x32_bf16(aq[mt][kf], bk[nt], sacc[mt][nt], 0, 0, 0);
            }
            bool full = (kv0 + 63 <= wq0);
#pragma unroll
            for (int mt = 0; mt < 2; mt++)
#pragma unroll
                for (int r = 0; r < 4; r++) {
                    int qg = wq0 + mt * 16 + (hi << 2) + r;
                    int prow = mt * 16 + (hi << 2) + r;
#pragma unroll
                    for (int nt = 0; nt < 4; nt++) {
                        float sv = sacc[mt][nt][r];
                        if (!full) {
                            int kvg = kv0 + nt * 16 + lr;
                            sv = (kvg <= qg) ? sv : -1e30f;
                        }
                        float p = fexp2(sv);
                        lacc[mt][r] += p;
                        Pl[prow][nt * 16 + lr] = f2bf_t(p);
                    }
                }
            // PV
#pragma unroll
            for (int kf = 0; kf < 2; kf++) {
                short8 pa[2];
#pragma unroll
                for (int mt = 0; mt < 2; mt++) pa[mt] = *(short8*)&Pl[mt * 16 + lr][kf * 32 + lk8];
#pragma unroll
                for (int mt = 0; mt < 2; mt++)
#pragma unroll
                    for (int nt = 0; nt < 4; nt++)
                        yacc[mt][nt] = __builtin_amdgcn_mfma_f32_16x16x32_bf16(pa[mt], bv[nt][kf], yacc[mt][nt], 0, 0, 0);
            }
        }
        __syncthreads();   // drains stage(t+1); buf[cur] free for reuse
    }

    if (bq < 4) {
#pragma unroll
        for (int mt = 0; mt < 2; mt++)
#pragma unroll
            for (int r = 0; r < 4; r++) {
                float l = lacc[mt][r];
                l += __shfl_xor(l, 1);
                l += __shfl_xor(l, 2);
                l += __shfl_xor(l, 4);
                l += __shfl_xor(l, 8);
                float inv = 1.f / l;
                int qg = wq0 + mt * 16 + (hi << 2) + r;
#pragma unroll
                for (int nt = 0; nt < 4; nt++)
                    y[((size_t)(bi * T + qg)) * 768 + hh * 64 + nt * 16 + lr] = f2bf(yacc[mt][nt][r] * inv);
            }
    } else {
        int g = bq >> 2, rr = bq & 3;
        int base = (g == 1) ? 2 * rr : (g == 2) ? 8 + 3 * rr : 20 + 4 * rr;
        int slab = bh * 36 + base + c;
        unsigned short* op = opart + (size_t)slab * 8192;
        float* lp = lpart + (size_t)slab * 128;
#pragma unroll
        for (int mt = 0; mt < 2; mt++)
#pragma unroll
            for (int r = 0; r < 4; r++) {
                float l = lacc[mt][r];
                l += __shfl_xor(l, 1);
                l += __shfl_xor(l, 2);
                l += __shfl_xor(l, 4);
                l += __shfl_xor(l, 8);
                int wrow = w * 32 + mt * 16 + (hi << 2) + r;
                if (lr == 0) lp[wrow] = l;
#pragma unroll
                for (int nt = 0; nt < 4; nt++)
                    op[(size_t)wrow * 64 + nt * 16 + lr] = f2bf(yacc[mt][nt][r]);
            }
    }
}

// ---------------- Combine split-KV partials: sum, normalize, write y ----------
__global__ __launch_bounds__(256) void attn_combine(const unsigned short* __restrict__ opart,
                                                    const float* __restrict__ lpart,
                                                    unsigned short* __restrict__ y) {
    const int T = 2048, H = 12;
    int bq = 4 + (int)blockIdx.x;
    int bh = blockIdx.y;
    int bi = bh / H, hh = bh - bi * H;
    int nchunk = (bq >> 2) + 1;
    int g = bq >> 2, rr = bq & 3;
    int base = (g == 1) ? 2 * rr : (g == 2) ? 8 + 3 * rr : 20 + 4 * rr;
    int tid = threadIdx.x;
    int row = tid >> 1, cb = (tid & 1) * 32;

    float l = 0.f;
    for (int c = 0; c < nchunk; c++) l += lpart[(size_t)(bh * 36 + base + c) * 128 + row];
    float inv = 1.f / l;

    float s[32];
#pragma unroll
    for (int j = 0; j < 32; j++) s[j] = 0.f;
    for (int c = 0; c < nchunk; c++) {
        const unsigned short* op = opart + ((size_t)(bh * 36 + base + c) * 128 + row) * 64 + cb;
#pragma unroll
        for (int v = 0; v < 4; v++) {
            short8 ob = *(const short8*)&op[v * 8];
#pragma unroll
            for (int j = 0; j < 8; j++) s[v * 8 + j] += bf2f((unsigned short)ob[j]);
        }
    }
    int qg = bq * 128 + row;
    unsigned short* yr = y + ((size_t)(bi * T + qg)) * 768 + hh * 64 + cb;
#pragma unroll
    for (int v = 0; v < 4; v++) {
        short8 ob;
#pragma unroll
        for (int j = 0; j < 8; j++) ob[j] = (short)f2bf(s[v * 8 + j] * inv);
        *(short8*)&yr[v * 8] = ob;
    }
}

extern "C" void kernel_launch(void* const* d_in, const int* in_sizes, int n_in,
                              void* d_out, int out_size, void* d_ws, size_t ws_size,
                              hipStream_t stream) {
    const float* x    = (const float*)d_in[0];
    const float* ln1w = (const float*)d_in[1];
    const float* ln1b = (const float*)d_in[2];
    const float* wqkv = (const float*)d_in[3];
    const float* bqkv = (const float*)d_in[4];
    const float* wproj= (const float*)d_in[5];
    const float* bproj= (const float*)d_in[6];
    const float* ln2w = (const float*)d_in[7];
    const float* ln2b = (const float*)d_in[8];
    const float* wfc1 = (const float*)d_in[9];
    const float* bfc1 = (const float*)d_in[10];
    const float* wfc2 = (const float*)d_in[11];
    const float* bfc2 = (const float*)d_in[12];
    float* out = (float*)d_out;

    char* ws = (char*)d_ws;
    size_t off = 0;
    auto alloc = [&](size_t bytes) { void* p = ws + off; off += (bytes + 255) & ~(size_t)255; return p; };

    const size_t MT = 4096;  // tokens
    unsigned short* wqkv_t = (unsigned short*)alloc(2304 * 768 * 2);
    unsigned short* wproj_t= (unsigned short*)alloc(768 * 768 * 2);
    unsigned short* wfc1_t = (unsigned short*)alloc(3072 * 768 * 2);
    unsigned short* wfc2_t = (unsigned short*)alloc(768 * 3072 * 2);
    unsigned short* h12    = (unsigned short*)alloc(MT * 768 * 2);
    float*          x1     = (float*)alloc(MT * 768 * 4);
    unsigned short* qs     = (unsigned short*)alloc(MT * 768 * 2);
    unsigned short* ks     = (unsigned short*)alloc(MT * 768 * 2);
    unsigned short* vt     = (unsigned short*)alloc(MT * 768 * 2);
    unsigned short* yb     = (unsigned short*)alloc(MT * 768 * 2);
    unsigned short* hm     = qs;  // [4096,3072] bf16 aliases qs..yb (exactly 4x)
    unsigned short* opart  = (unsigned short*)alloc(24 * 36 * 8192 * 2);
    float*          lpart  = (float*)alloc(24 * 36 * 128 * 4);

    // fc2 split-K partials alias dead regions at fc2 time
    unsigned short* p0 = (unsigned short*)ws;
    unsigned short* p1 = opart;
    unsigned short* p2 = (unsigned short*)((char*)opart + (size_t)MT * 768 * 2);
    unsigned short* p3 = h12;

    wt_all_kernel<<<dim3(6912), 256, 0, stream>>>(wqkv, wqkv_t, wproj, wproj_t,
                                                  wfc1, wfc1_t, wfc2, wfc2_t);

    ln_kernel<<<4096, 256, 0, stream>>>(x, ln1w, ln1b, h12);
    gemm_kernel<0><<<dim3(18, 32), 256, 0, stream>>>(h12, wqkv_t, bqkv, nullptr, nullptr, qs, ks, vt, 768, 768);
    attn_kernel<<<dim3(40, 24), 256, 0, stream>>>(qs, ks, vt, yb, opart, lpart);
    attn_combine<<<dim3(12, 24), 256, 0, stream>>>(opart, lpart, yb);
    gemm_kernel<1><<<dim3(6, 32), 256, 0, stream>>>(yb, wproj_t, bproj, x, x1, nullptr, nullptr, nullptr, 768, 768);
    ln_kernel<<<4096, 256, 0, stream>>>(x1, ln2w, ln2b, h12);
    gemm_kernel<2><<<dim3(24, 32), 256, 0, stream>>>(h12, wfc1_t, bfc1, nullptr, nullptr, hm, nullptr, nullptr, 768, 768);
    gemm_kernel<4><<<dim3(24, 32), 256, 0, stream>>>(hm, wfc2_t, nullptr, nullptr, (float*)p3, p0, p1, p2, 3072, 768);
    sk_combine<<<dim3(1536), 256, 0, stream>>>(p0, p1, p2, p3, bfc2, x1, out);
}

// Round 16
// 211.461 us; speedup vs baseline: 1.2126x; 1.2126x over previous
//
#include <hip/hip_runtime.h>
#include <math.h>

typedef __attribute__((ext_vector_type(8))) short short8;
typedef __attribute__((ext_vector_type(4))) float floatx4;

__device__ __forceinline__ unsigned short f2bf(float f) {
    union { float f; unsigned u; } v; v.f = f;
    unsigned r = v.u + 0x7fffu + ((v.u >> 16) & 1u);
    return (unsigned short)(r >> 16);
}

// truncating f32->bf16 (1 VALU op); P-staging only (error << threshold)
__device__ __forceinline__ unsigned short f2bf_t(float f) {
    union { float f; unsigned u; } v; v.f = f;
    return (unsigned short)(v.u >> 16);
}

__device__ __forceinline__ float bf2f(unsigned short h) {
    union { unsigned u; float f; } v; v.u = ((unsigned)h) << 16; return v.f;
}

__device__ __forceinline__ float fexp2(float x) {
#if __has_builtin(__builtin_amdgcn_exp2f)
    return __builtin_amdgcn_exp2f(x);
#else
    return __expf(x * 0.69314718056f);
#endif
}

// async global->LDS, 16B per lane; lds base must be wave-uniform (HW adds lane*16)
__device__ __forceinline__ void gload16(const unsigned short* g, unsigned short* l) {
    __builtin_amdgcn_global_load_lds(
        (const __attribute__((address_space(1))) unsigned int*)g,
        (__attribute__((address_space(3))) unsigned int*)l, 16, 0, 0);
}

// ---------------- LayerNorm (fp32 in -> bf16 out), one block per row of 768 ----
__global__ __launch_bounds__(256) void ln_kernel(const float* __restrict__ x,
                                                 const float* __restrict__ w,
                                                 const float* __restrict__ b,
                                                 unsigned short* __restrict__ o) {
    int row = blockIdx.x, tid = threadIdx.x;
    const float* xr = x + (size_t)row * 768;
    float v0 = xr[tid], v1 = xr[tid + 256], v2 = xr[tid + 512];
    float s = v0 + v1 + v2, ss = v0 * v0 + v1 * v1 + v2 * v2;
#pragma unroll
    for (int o_ = 32; o_; o_ >>= 1) { s += __shfl_xor(s, o_); ss += __shfl_xor(ss, o_); }
    __shared__ float red[8];
    if ((tid & 63) == 0) { red[tid >> 6] = s; red[(tid >> 6) + 4] = ss; }
    __syncthreads();
    s = red[0] + red[1] + red[2] + red[3];
    ss = red[4] + red[5] + red[6] + red[7];
    float mu = s * (1.f / 768.f);
    float var = ss * (1.f / 768.f) - mu * mu;
    float inv = rsqrtf(var + 1e-5f);
    unsigned short* orow = o + (size_t)row * 768;
    orow[tid]       = f2bf((v0 - mu) * inv * w[tid]       + b[tid]);
    orow[tid + 256] = f2bf((v1 - mu) * inv * w[tid + 256] + b[tid + 256]);
    orow[tid + 512] = f2bf((v2 - mu) * inv * w[tid + 512] + b[tid + 512]);
}

// ------- All 4 weight converts fused: fp32 [K,N] -> bf16 transposed [N,K] -----
__global__ __launch_bounds__(256) void wt_all_kernel(
    const float* __restrict__ w0, unsigned short* __restrict__ t0,
    const float* __restrict__ w1, unsigned short* __restrict__ t1,
    const float* __restrict__ w2, unsigned short* __restrict__ t2,
    const float* __restrict__ w3, unsigned short* __restrict__ t3) {
    int bid = (int)blockIdx.x;
    const float* w; unsigned short* wt; int K, N, bx, by;
    if (bid < 1728)      { w = w0; wt = t0; K = 768;  N = 2304; int l = bid;        bx = l % 72; by = l / 72; }
    else if (bid < 2304) { w = w1; wt = t1; K = 768;  N = 768;  int l = bid - 1728; bx = l % 24; by = l / 24; }
    else if (bid < 4608) { w = w2; wt = t2; K = 768;  N = 3072; int l = bid - 2304; bx = l % 96; by = l / 96; }
    else                 { w = w3; wt = t3; K = 3072; N = 768;  int l = bid - 4608; bx = l % 24; by = l / 24; }
    __shared__ float t[32][33];
    int n0 = bx * 32, k0 = by * 32;
    int tx = threadIdx.x & 31, ty = threadIdx.x >> 5;
#pragma unroll
    for (int i = 0; i < 32; i += 8)
        t[ty + i][tx] = w[(size_t)(k0 + ty + i) * N + n0 + tx];
    __syncthreads();
#pragma unroll
    for (int i = 0; i < 32; i += 8)
        wt[(size_t)(n0 + ty + i) * K + k0 + tx] = f2bf(t[tx][ty + i]);
}

// ---------------- GEMM: C[M,N] = A[M,K](bf16) @ Bt[N,K](bf16)^T, epilogues -----
// 2-phase double-buffered pipeline (best measured over 5 structure variants)
// + XCD-chunked swizzle.
// EPI 0: qkv split; EPI 1: +bias+resid fp32; EPI 2: gelu; EPI 4: split-K partial.
template <int EPI>
__global__ __launch_bounds__(256) void gemm_kernel(
    const unsigned short* __restrict__ A, const unsigned short* __restrict__ Bt,
    const float* __restrict__ bias, const float* __restrict__ resid,
    float* __restrict__ fout, unsigned short* __restrict__ o0,
    unsigned short* __restrict__ o1, unsigned short* __restrict__ o2,
    int K, int Kcnt) {
    __shared__ unsigned short Al[2][128 * 32];
    __shared__ unsigned short Bl[2][128 * 32];
    int tid = threadIdx.x, lane = tid & 63, w = tid >> 6;
    int wm = w >> 1, wn = w & 1;
    int nwg = (int)(gridDim.x * gridDim.y);
    int wgid = (int)(blockIdx.y * gridDim.x + blockIdx.x);
    int logical = (wgid & 7) * (nwg >> 3) + (wgid >> 3);
    int by = logical & 31, bx = logical >> 5;
    int m0 = by * 128;
    int n0, kof = 0, chunk = 0;
    if (EPI == 4) {
        n0 = (bx % 6) * 128;
        chunk = bx / 6;
        kof = chunk * Kcnt;
    } else {
        n0 = bx * 128;
    }
    int lr = lane & 15, lk = (lane >> 4) << 3;

    int srow = w * 32 + (lane >> 2);
    int sko = (lane & 3) << 3;
    const unsigned short* Ab = A + (size_t)(m0 + srow) * K + kof + sko;
    const unsigned short* Bb = Bt + (size_t)(n0 + srow) * K + kof + sko;

    floatx4 acc[4][4];
#pragma unroll
    for (int i = 0; i < 4; i++)
#pragma unroll
        for (int j = 0; j < 4; j++) acc[i][j] = (floatx4){0.f, 0.f, 0.f, 0.f};

    int nk = Kcnt >> 5;
    auto stage = [&](int buf, int t) {
        int k0 = t << 5;
        unsigned short* Alp = &Al[buf][(w * 32) * 32];
        unsigned short* Blp = &Bl[buf][(w * 32) * 32];
        gload16(Ab + k0, Alp);
        gload16(Ab + 16 * K + k0, Alp + 16 * 32);
        gload16(Bb + k0, Blp);
        gload16(Bb + 16 * K + k0, Blp + 16 * 32);
    };

    stage(0, 0);
    for (int t = 0; t < nk; t++) {
        int cur = t & 1;
        __syncthreads();                        // stage(t) landed; buf[cur^1] free
        if (t + 1 < nk) stage(cur ^ 1, t + 1);  // flies under compute(t)
        short8 af[4], bfr[4];
#pragma unroll
        for (int mt = 0; mt < 4; mt++) af[mt] = *(short8*)&Al[cur][(wm * 64 + mt * 16 + lr) * 32 + lk];
#pragma unroll
        for (int nt = 0; nt < 4; nt++) bfr[nt] = *(short8*)&Bl[cur][(wn * 64 + nt * 16 + lr) * 32 + lk];
#pragma unroll
        for (int mt = 0; mt < 4; mt++)
#pragma unroll
            for (int nt = 0; nt < 4; nt++)
                acc[mt][nt] = __builtin_amdgcn_mfma_f32_16x16x32_bf16(af[mt], bfr[nt], acc[mt][nt], 0, 0, 0);
    }

    int mb = m0 + wm * 64, nb = n0 + wn * 64;
    int sec = 0;
    if (EPI == 0) sec = n0 / 768;
#pragma unroll
    for (int mt = 0; mt < 4; mt++)
#pragma unroll
        for (int nt = 0; nt < 4; nt++)
#pragma unroll
            for (int r = 0; r < 4; r++) {
                int mrow = mb + mt * 16 + ((lane >> 4) << 2) + r;
                int ncol = nb + nt * 16 + lr;
                float val = acc[mt][nt][r];
                if (EPI != 4) val += bias[ncol];
                if (EPI == 0) {
                    int f = ncol - sec * 768;
                    int h = f >> 6, d = f & 63;
                    int bb = mrow >> 11, t = mrow & 2047;
                    if (sec == 0)
                        o0[((size_t)(bb * 12 + h) * 2048 + t) * 64 + d] = f2bf(val * 0.1803368801f);
                    else if (sec == 1)
                        o1[((size_t)(bb * 12 + h) * 2048 + t) * 64 + d] = f2bf(val);
                    else
                        o2[((size_t)(bb * 12 + h) * 64 + d) * 2048 + t] = f2bf(val);
                } else if (EPI == 1) {
                    fout[(size_t)mrow * 768 + ncol] = val + resid[(size_t)mrow * 768 + ncol];
                } else if (EPI == 2) {
                    float g = 0.5f * val * (1.f + erff(val * 0.70710678118f));
                    o0[(size_t)mrow * 3072 + ncol] = f2bf(g);
                } else if (EPI == 4) {
                    unsigned short* op = (chunk == 0) ? o0 : (chunk == 1) ? o1
                                       : (chunk == 2) ? o2 : (unsigned short*)fout;
                    op[(size_t)mrow * 768 + ncol] = f2bf(val);
                }
            }
}

// -------- split-K combine: out = p0+p1+p2+p3 + bias + resid (fp32), N=768 -----
__global__ __launch_bounds__(256) void sk_combine(
    const unsigned short* __restrict__ p0, const unsigned short* __restrict__ p1,
    const unsigned short* __restrict__ p2, const unsigned short* __restrict__ p3,
    const float* __restrict__ bias, const float* __restrict__ resid,
    float* __restrict__ out) {
    int i = blockIdx.x * 256 + threadIdx.x;
    size_t base = (size_t)i * 8;
    int col = (int)(base % 768);
    short8 a0 = *(const short8*)&p0[base];
    short8 a1 = *(const short8*)&p1[base];
    short8 a2 = *(const short8*)&p2[base];
    short8 a3 = *(const short8*)&p3[base];
#pragma unroll
    for (int j = 0; j < 8; j++) {
        float s = bf2f((unsigned short)a0[j]) + bf2f((unsigned short)a1[j]) +
                  bf2f((unsigned short)a2[j]) + bf2f((unsigned short)a3[j]);
        out[base + j] = s + bias[col + j] + resid[base + j];
    }
}

// ---------------- Flash attention (causal), split-KV across blocks ------------
// Block = (bq, c): q-rows [bq*128, +128), KV tiles [c*8, min(c*8+8, 2bq+2)).
// K staged in LDS (XOR-swizzled double-buffered gload_lds); V direct from global.
// No-max softmax; q pre-scaled by log2e/8. P staged with TRUNCATING bf16 (1 op).
__global__ __launch_bounds__(256) void attn_kernel(const unsigned short* __restrict__ q_s,
                                                   const unsigned short* __restrict__ k_s,
                                                   const unsigned short* __restrict__ v_t,
                                                   unsigned short* __restrict__ y,
                                                   unsigned short* __restrict__ opart,
                                                   float* __restrict__ lpart) {
    __shared__ unsigned short KVs[2][4096];
    __shared__ unsigned short Pls[4][32][72];
    const int T = 2048, H = 12;
    int tid = threadIdx.x, lane = tid & 63, w = tid >> 6;
    int xx = (int)blockIdx.x;
    int bq, c;
    if (xx < 16)      { c = 0; bq = xx; }
    else if (xx < 28) { c = 1; bq = xx - 12; }
    else if (xx < 36) { c = 2; bq = xx - 20; }
    else              { c = 3; bq = xx - 24; }
    int bh = blockIdx.y;
    int bi = bh / H, hh = bh - bi * H;
    const unsigned short* qp = q_s + (size_t)bh * T * 64;
    const unsigned short* kp = k_s + (size_t)bh * T * 64;
    const unsigned short* vp = v_t + (size_t)bh * 64 * T;
    int wq0 = bq * 128 + w * 32;
    int lr = lane & 15, lk8 = (lane >> 4) << 3, hi = lane >> 4;
    int nt_blk = 2 * bq + 2;
    int t0 = c * 8;
    int t1 = t0 + 8 < nt_blk ? t0 + 8 : nt_blk;

    unsigned short (*Pl)[72] = Pls[w];
    int srow = tid >> 3, ssl = tid & 7;

    auto stage = [&](int buf, int t) {
        int kv0 = t * 64;
        unsigned short* base = &KVs[buf][(tid >> 6) * 512];
#pragma unroll
        for (int h = 0; h < 2; h++) {
            int r = srow + h * 32;
            int ss = ssl ^ (r & 7);
            gload16(kp + (size_t)(kv0 + r) * 64 + ss * 8, base + h * 2048);
        }
    };

    short8 aq[2][2];
#pragma unroll
    for (int mt = 0; mt < 2; mt++)
#pragma unroll
        for (int kf = 0; kf < 2; kf++)
            aq[mt][kf] = *(const short8*)&qp[(size_t)(wq0 + mt * 16 + lr) * 64 + kf * 32 + lk8];

    floatx4 yacc[2][4];
    float lacc[2][4];
#pragma unroll
    for (int i = 0; i < 2; i++)
#pragma unroll
        for (int j = 0; j < 4; j++) {
            yacc[i][j] = (floatx4){0.f, 0.f, 0.f, 0.f};
            lacc[i][j] = 0.f;
        }

    stage(0, t0);
    __syncthreads();

    for (int t = t0; t < t1; t++) {
        int cur = (t - t0) & 1;
        if (t + 1 < t1) stage(cur ^ 1, t + 1);
        int kv0 = t * 64;
        if (kv0 <= wq0 + 31) {
            const unsigned short* Kt = &KVs[cur][0];
            floatx4 sacc[2][4];
#pragma unroll
            for (int i = 0; i < 2; i++)
#pragma unroll
                for (int j = 0; j < 4; j++) sacc[i][j] = (floatx4){0.f, 0.f, 0.f, 0.f};
#pragma unroll
            for (int kf = 0; kf < 2; kf++) {
                int sl = ((kf << 2) | hi) ^ (lr & 7);
                short8 bk[4];
#pragma unroll
                for (int nt = 0; nt < 4; nt++)
                    bk[nt] = *(const short8*)&Kt[(nt * 16 + lr) * 64 + sl * 8];
#pragma unroll
                for (int mt = 0; mt < 2; mt++)
#pragma unroll
                    for (int nt = 0; nt < 4; nt++)
                        sacc[mt][nt] = __builtin_amdgcn_mfma_f32_16x16x32_bf16(aq[mt][kf], bk[nt], sacc[mt][nt], 0, 0, 0);
            }
            // V direct from global; issued early, consumed after softmax
            short8 bv[4][2];
#pragma unroll
            for (int nt = 0; nt < 4; nt++)
#pragma unroll
                for (int kf = 0; kf < 2; kf++)
                    bv[nt][kf] = *(const short8*)&vp[(size_t)(nt * 16 + lr) * T + kv0 + kf * 32 + lk8];
            bool full = (kv0 + 63 <= wq0);
#pragma unroll
            for (int mt = 0; mt < 2; mt++)
#pragma unroll
                for (int r = 0; r < 4; r++) {
                    int qg = wq0 + mt * 16 + (hi << 2) + r;
                    int prow = mt * 16 + (hi << 2) + r;
#pragma unroll
                    for (int nt = 0; nt < 4; nt++) {
                        float sv = sacc[mt][nt][r];
                        if (!full) {
                            int kvg = kv0 + nt * 16 + lr;
                            sv = (kvg <= qg) ? sv : -1e30f;
                        }
                        float p = fexp2(sv);
                        lacc[mt][r] += p;
                        Pl[prow][nt * 16 + lr] = f2bf_t(p);   // truncating: 1 VALU op
                    }
                }
            // PV
#pragma unroll
            for (int kf = 0; kf < 2; kf++) {
                short8 pa[2];
#pragma unroll
                for (int mt = 0; mt < 2; mt++) pa[mt] = *(short8*)&Pl[mt * 16 + lr][kf * 32 + lk8];
#pragma unroll
                for (int mt = 0; mt < 2; mt++)
#pragma unroll
                    for (int nt = 0; nt < 4; nt++)
                        yacc[mt][nt] = __builtin_amdgcn_mfma_f32_16x16x32_bf16(pa[mt], bv[nt][kf], yacc[mt][nt], 0, 0, 0);
            }
        }
        __syncthreads();
    }

    if (bq < 4) {
#pragma unroll
        for (int mt = 0; mt < 2; mt++)
#pragma unroll
            for (int r = 0; r < 4; r++) {
                float l = lacc[mt][r];
                l += __shfl_xor(l, 1);
                l += __shfl_xor(l, 2);
                l += __shfl_xor(l, 4);
                l += __shfl_xor(l, 8);
                float inv = 1.f / l;
                int qg = wq0 + mt * 16 + (hi << 2) + r;
#pragma unroll
                for (int nt = 0; nt < 4; nt++)
                    y[((size_t)(bi * T + qg)) * 768 + hh * 64 + nt * 16 + lr] = f2bf(yacc[mt][nt][r] * inv);
            }
    } else {
        int g = bq >> 2, rr = bq & 3;
        int base = (g == 1) ? 2 * rr : (g == 2) ? 8 + 3 * rr : 20 + 4 * rr;
        int slab = bh * 36 + base + c;
        unsigned short* op = opart + (size_t)slab * 8192;
        float* lp = lpart + (size_t)slab * 128;
#pragma unroll
        for (int mt = 0; mt < 2; mt++)
#pragma unroll
            for (int r = 0; r < 4; r++) {
                float l = lacc[mt][r];
                l += __shfl_xor(l, 1);
                l += __shfl_xor(l, 2);
                l += __shfl_xor(l, 4);
                l += __shfl_xor(l, 8);
                int wrow = w * 32 + mt * 16 + (hi << 2) + r;
                if (lr == 0) lp[wrow] = l;
#pragma unroll
                for (int nt = 0; nt < 4; nt++)
                    op[(size_t)wrow * 64 + nt * 16 + lr] = f2bf(yacc[mt][nt][r]);
            }
    }
}

// ---------------- Combine split-KV partials: sum, normalize, write y ----------
__global__ __launch_bounds__(256) void attn_combine(const unsigned short* __restrict__ opart,
                                                    const float* __restrict__ lpart,
                                                    unsigned short* __restrict__ y) {
    const int T = 2048, H = 12;
    int bq = 4 + (int)blockIdx.x;
    int bh = blockIdx.y;
    int bi = bh / H, hh = bh - bi * H;
    int nchunk = (bq >> 2) + 1;
    int g = bq >> 2, rr = bq & 3;
    int base = (g == 1) ? 2 * rr : (g == 2) ? 8 + 3 * rr : 20 + 4 * rr;
    int tid = threadIdx.x;
    int row = tid >> 1, cb = (tid & 1) * 32;

    float l = 0.f;
    for (int c = 0; c < nchunk; c++) l += lpart[(size_t)(bh * 36 + base + c) * 128 + row];
    float inv = 1.f / l;

    float s[32];
#pragma unroll
    for (int j = 0; j < 32; j++) s[j] = 0.f;
    for (int c = 0; c < nchunk; c++) {
        const unsigned short* op = opart + ((size_t)(bh * 36 + base + c) * 128 + row) * 64 + cb;
#pragma unroll
        for (int v = 0; v < 4; v++) {
            short8 ob = *(const short8*)&op[v * 8];
#pragma unroll
            for (int j = 0; j < 8; j++) s[v * 8 + j] += bf2f((unsigned short)ob[j]);
        }
    }
    int qg = bq * 128 + row;
    unsigned short* yr = y + ((size_t)(bi * T + qg)) * 768 + hh * 64 + cb;
#pragma unroll
    for (int v = 0; v < 4; v++) {
        short8 ob;
#pragma unroll
        for (int j = 0; j < 8; j++) ob[j] = (short)f2bf(s[v * 8 + j] * inv);
        *(short8*)&yr[v * 8] = ob;
    }
}

extern "C" void kernel_launch(void* const* d_in, const int* in_sizes, int n_in,
                              void* d_out, int out_size, void* d_ws, size_t ws_size,
                              hipStream_t stream) {
    const float* x    = (const float*)d_in[0];
    const float* ln1w = (const float*)d_in[1];
    const float* ln1b = (const float*)d_in[2];
    const float* wqkv = (const float*)d_in[3];
    const float* bqkv = (const float*)d_in[4];
    const float* wproj= (const float*)d_in[5];
    const float* bproj= (const float*)d_in[6];
    const float* ln2w = (const float*)d_in[7];
    const float* ln2b = (const float*)d_in[8];
    const float* wfc1 = (const float*)d_in[9];
    const float* bfc1 = (const float*)d_in[10];
    const float* wfc2 = (const float*)d_in[11];
    const float* bfc2 = (const float*)d_in[12];
    float* out = (float*)d_out;

    char* ws = (char*)d_ws;
    size_t off = 0;
    auto alloc = [&](size_t bytes) { void* p = ws + off; off += (bytes + 255) & ~(size_t)255; return p; };

    const size_t MT = 4096;  // tokens
    unsigned short* wqkv_t = (unsigned short*)alloc(2304 * 768 * 2);
    unsigned short* wproj_t= (unsigned short*)alloc(768 * 768 * 2);
    unsigned short* wfc1_t = (unsigned short*)alloc(3072 * 768 * 2);
    unsigned short* wfc2_t = (unsigned short*)alloc(768 * 3072 * 2);
    unsigned short* h12    = (unsigned short*)alloc(MT * 768 * 2);
    float*          x1     = (float*)alloc(MT * 768 * 4);
    unsigned short* qs     = (unsigned short*)alloc(MT * 768 * 2);
    unsigned short* ks     = (unsigned short*)alloc(MT * 768 * 2);
    unsigned short* vt     = (unsigned short*)alloc(MT * 768 * 2);
    unsigned short* yb     = (unsigned short*)alloc(MT * 768 * 2);
    unsigned short* hm     = qs;  // [4096,3072] bf16 aliases qs..yb (exactly 4x)
    unsigned short* opart  = (unsigned short*)alloc(24 * 36 * 8192 * 2);
    float*          lpart  = (float*)alloc(24 * 36 * 128 * 4);

    // fc2 split-K partials alias dead regions at fc2 time
    unsigned short* p0 = (unsigned short*)ws;
    unsigned short* p1 = opart;
    unsigned short* p2 = (unsigned short*)((char*)opart + (size_t)MT * 768 * 2);
    unsigned short* p3 = h12;

    wt_all_kernel<<<dim3(6912), 256, 0, stream>>>(wqkv, wqkv_t, wproj, wproj_t,
                                                  wfc1, wfc1_t, wfc2, wfc2_t);

    ln_kernel<<<4096, 256, 0, stream>>>(x, ln1w, ln1b, h12);
    gemm_kernel<0><<<dim3(18, 32), 256, 0, stream>>>(h12, wqkv_t, bqkv, nullptr, nullptr, qs, ks, vt, 768, 768);
    attn_kernel<<<dim3(40, 24), 256, 0, stream>>>(qs, ks, vt, yb, opart, lpart);
    attn_combine<<<dim3(12, 24), 256, 0, stream>>>(opart, lpart, yb);
    gemm_kernel<1><<<dim3(6, 32), 256, 0, stream>>>(yb, wproj_t, bproj, x, x1, nullptr, nullptr, nullptr, 768, 768);
    ln_kernel<<<4096, 256, 0, stream>>>(x1, ln2w, ln2b, h12);
    gemm_kernel<2><<<dim3(24, 32), 256, 0, stream>>>(h12, wfc1_t, bfc1, nullptr, nullptr, hm, nullptr, nullptr, 768, 768);
    gemm_kernel<4><<<dim3(24, 32), 256, 0, stream>>>(hm, wfc2_t, nullptr, nullptr, (float*)p3, p0, p1, p2, 3072, 768);
    sk_combine<<<dim3(1536), 256, 0, stream>>>(p0, p1, p2, p3, bfc2, x1, out);
}

// Round 17
// 206.408 us; speedup vs baseline: 1.2423x; 1.0245x over previous
//
#include <hip/hip_runtime.h>
#include <math.h>

typedef __attribute__((ext_vector_type(8))) short short8;
typedef __attribute__((ext_vector_type(4))) float floatx4;

__device__ __forceinline__ unsigned short f2bf(float f) {
    union { float f; unsigned u; } v; v.f = f;
    unsigned r = v.u + 0x7fffu + ((v.u >> 16) & 1u);
    return (unsigned short)(r >> 16);
}

// truncating f32->bf16 (1 VALU op); P-staging only (error << threshold)
__device__ __forceinline__ unsigned short f2bf_t(float f) {
    union { float f; unsigned u; } v; v.f = f;
    return (unsigned short)(v.u >> 16);
}

__device__ __forceinline__ float bf2f(unsigned short h) {
    union { unsigned u; float f; } v; v.u = ((unsigned)h) << 16; return v.f;
}

__device__ __forceinline__ float fexp2(float x) {
#if __has_builtin(__builtin_amdgcn_exp2f)
    return __builtin_amdgcn_exp2f(x);
#else
    return __expf(x * 0.69314718056f);
#endif
}

// async global->LDS, 16B per lane; lds base must be wave-uniform (HW adds lane*16)
__device__ __forceinline__ void gload16(const unsigned short* g, unsigned short* l) {
    __builtin_amdgcn_global_load_lds(
        (const __attribute__((address_space(1))) unsigned int*)g,
        (__attribute__((address_space(3))) unsigned int*)l, 16, 0, 0);
}

// ---------------- LayerNorm (fp32 in -> bf16 out), one block per row of 768 ----
__global__ __launch_bounds__(256) void ln_kernel(const float* __restrict__ x,
                                                 const float* __restrict__ w,
                                                 const float* __restrict__ b,
                                                 unsigned short* __restrict__ o) {
    int row = blockIdx.x, tid = threadIdx.x;
    const float* xr = x + (size_t)row * 768;
    float v0 = xr[tid], v1 = xr[tid + 256], v2 = xr[tid + 512];
    float s = v0 + v1 + v2, ss = v0 * v0 + v1 * v1 + v2 * v2;
#pragma unroll
    for (int o_ = 32; o_; o_ >>= 1) { s += __shfl_xor(s, o_); ss += __shfl_xor(ss, o_); }
    __shared__ float red[8];
    if ((tid & 63) == 0) { red[tid >> 6] = s; red[(tid >> 6) + 4] = ss; }
    __syncthreads();
    s = red[0] + red[1] + red[2] + red[3];
    ss = red[4] + red[5] + red[6] + red[7];
    float mu = s * (1.f / 768.f);
    float var = ss * (1.f / 768.f) - mu * mu;
    float inv = rsqrtf(var + 1e-5f);
    unsigned short* orow = o + (size_t)row * 768;
    orow[tid]       = f2bf((v0 - mu) * inv * w[tid]       + b[tid]);
    orow[tid + 256] = f2bf((v1 - mu) * inv * w[tid + 256] + b[tid + 256]);
    orow[tid + 512] = f2bf((v2 - mu) * inv * w[tid + 512] + b[tid + 512]);
}

// ------- All 4 weight converts fused: fp32 [K,N] -> bf16 transposed [N,K] -----
__global__ __launch_bounds__(256) void wt_all_kernel(
    const float* __restrict__ w0, unsigned short* __restrict__ t0,
    const float* __restrict__ w1, unsigned short* __restrict__ t1,
    const float* __restrict__ w2, unsigned short* __restrict__ t2,
    const float* __restrict__ w3, unsigned short* __restrict__ t3) {
    int bid = (int)blockIdx.x;
    const float* w; unsigned short* wt; int K, N, bx, by;
    if (bid < 1728)      { w = w0; wt = t0; K = 768;  N = 2304; int l = bid;        bx = l % 72; by = l / 72; }
    else if (bid < 2304) { w = w1; wt = t1; K = 768;  N = 768;  int l = bid - 1728; bx = l % 24; by = l / 24; }
    else if (bid < 4608) { w = w2; wt = t2; K = 768;  N = 3072; int l = bid - 2304; bx = l % 96; by = l / 96; }
    else                 { w = w3; wt = t3; K = 3072; N = 768;  int l = bid - 4608; bx = l % 24; by = l / 24; }
    __shared__ float t[32][33];
    int n0 = bx * 32, k0 = by * 32;
    int tx = threadIdx.x & 31, ty = threadIdx.x >> 5;
#pragma unroll
    for (int i = 0; i < 32; i += 8)
        t[ty + i][tx] = w[(size_t)(k0 + ty + i) * N + n0 + tx];
    __syncthreads();
#pragma unroll
    for (int i = 0; i < 32; i += 8)
        wt[(size_t)(n0 + ty + i) * K + k0 + tx] = f2bf(t[tx][ty + i]);
}

// ---------------- GEMM: C[M,N] = A[M,K](bf16) @ Bt[N,K](bf16)^T, epilogues -----
// 2-phase double-buffered pipeline (best measured over 5 structure variants)
// + XCD-chunked swizzle.
// EPI 0: qkv split; EPI 1: +bias+resid fp32; EPI 2: gelu; EPI 4: split-K partial.
template <int EPI>
__global__ __launch_bounds__(256) void gemm_kernel(
    const unsigned short* __restrict__ A, const unsigned short* __restrict__ Bt,
    const float* __restrict__ bias, const float* __restrict__ resid,
    float* __restrict__ fout, unsigned short* __restrict__ o0,
    unsigned short* __restrict__ o1, unsigned short* __restrict__ o2,
    int K, int Kcnt) {
    __shared__ unsigned short Al[2][128 * 32];
    __shared__ unsigned short Bl[2][128 * 32];
    int tid = threadIdx.x, lane = tid & 63, w = tid >> 6;
    int wm = w >> 1, wn = w & 1;
    int nwg = (int)(gridDim.x * gridDim.y);
    int wgid = (int)(blockIdx.y * gridDim.x + blockIdx.x);
    int logical = (wgid & 7) * (nwg >> 3) + (wgid >> 3);
    int by = logical & 31, bx = logical >> 5;
    int m0 = by * 128;
    int n0, kof = 0, chunk = 0;
    if (EPI == 4) {
        n0 = (bx % 6) * 128;
        chunk = bx / 6;
        kof = chunk * Kcnt;
    } else {
        n0 = bx * 128;
    }
    int lr = lane & 15, lk = (lane >> 4) << 3;

    int srow = w * 32 + (lane >> 2);
    int sko = (lane & 3) << 3;
    const unsigned short* Ab = A + (size_t)(m0 + srow) * K + kof + sko;
    const unsigned short* Bb = Bt + (size_t)(n0 + srow) * K + kof + sko;

    floatx4 acc[4][4];
#pragma unroll
    for (int i = 0; i < 4; i++)
#pragma unroll
        for (int j = 0; j < 4; j++) acc[i][j] = (floatx4){0.f, 0.f, 0.f, 0.f};

    int nk = Kcnt >> 5;
    auto stage = [&](int buf, int t) {
        int k0 = t << 5;
        unsigned short* Alp = &Al[buf][(w * 32) * 32];
        unsigned short* Blp = &Bl[buf][(w * 32) * 32];
        gload16(Ab + k0, Alp);
        gload16(Ab + 16 * K + k0, Alp + 16 * 32);
        gload16(Bb + k0, Blp);
        gload16(Bb + 16 * K + k0, Blp + 16 * 32);
    };

    stage(0, 0);
    for (int t = 0; t < nk; t++) {
        int cur = t & 1;
        __syncthreads();                        // stage(t) landed; buf[cur^1] free
        if (t + 1 < nk) stage(cur ^ 1, t + 1);  // flies under compute(t)
        short8 af[4], bfr[4];
#pragma unroll
        for (int mt = 0; mt < 4; mt++) af[mt] = *(short8*)&Al[cur][(wm * 64 + mt * 16 + lr) * 32 + lk];
#pragma unroll
        for (int nt = 0; nt < 4; nt++) bfr[nt] = *(short8*)&Bl[cur][(wn * 64 + nt * 16 + lr) * 32 + lk];
#pragma unroll
        for (int mt = 0; mt < 4; mt++)
#pragma unroll
            for (int nt = 0; nt < 4; nt++)
                acc[mt][nt] = __builtin_amdgcn_mfma_f32_16x16x32_bf16(af[mt], bfr[nt], acc[mt][nt], 0, 0, 0);
    }

    int mb = m0 + wm * 64, nb = n0 + wn * 64;
    int sec = 0;
    if (EPI == 0) sec = n0 / 768;
#pragma unroll
    for (int mt = 0; mt < 4; mt++)
#pragma unroll
        for (int nt = 0; nt < 4; nt++)
#pragma unroll
            for (int r = 0; r < 4; r++) {
                int mrow = mb + mt * 16 + ((lane >> 4) << 2) + r;
                int ncol = nb + nt * 16 + lr;
                float val = acc[mt][nt][r];
                if (EPI != 4) val += bias[ncol];
                if (EPI == 0) {
                    int f = ncol - sec * 768;
                    int h = f >> 6, d = f & 63;
                    int bb = mrow >> 11, t = mrow & 2047;
                    if (sec == 0)
                        o0[((size_t)(bb * 12 + h) * 2048 + t) * 64 + d] = f2bf(val * 0.1803368801f);
                    else if (sec == 1)
                        o1[((size_t)(bb * 12 + h) * 2048 + t) * 64 + d] = f2bf(val);
                    else
                        o2[((size_t)(bb * 12 + h) * 64 + d) * 2048 + t] = f2bf(val);
                } else if (EPI == 1) {
                    fout[(size_t)mrow * 768 + ncol] = val + resid[(size_t)mrow * 768 + ncol];
                } else if (EPI == 2) {
                    float g = 0.5f * val * (1.f + erff(val * 0.70710678118f));
                    o0[(size_t)mrow * 3072 + ncol] = f2bf(g);
                } else if (EPI == 4) {
                    unsigned short* op = (chunk == 0) ? o0 : (chunk == 1) ? o1
                                       : (chunk == 2) ? o2 : (unsigned short*)fout;
                    op[(size_t)mrow * 768 + ncol] = f2bf(val);
                }
            }
}

// -------- split-K combine: out = p0+p1+p2+p3 + bias + resid (fp32), N=768 -----
__global__ __launch_bounds__(256) void sk_combine(
    const unsigned short* __restrict__ p0, const unsigned short* __restrict__ p1,
    const unsigned short* __restrict__ p2, const unsigned short* __restrict__ p3,
    const float* __restrict__ bias, const float* __restrict__ resid,
    float* __restrict__ out) {
    int i = blockIdx.x * 256 + threadIdx.x;
    size_t base = (size_t)i * 8;
    int col = (int)(base % 768);
    short8 a0 = *(const short8*)&p0[base];
    short8 a1 = *(const short8*)&p1[base];
    short8 a2 = *(const short8*)&p2[base];
    short8 a3 = *(const short8*)&p3[base];
#pragma unroll
    for (int j = 0; j < 8; j++) {
        float s = bf2f((unsigned short)a0[j]) + bf2f((unsigned short)a1[j]) +
                  bf2f((unsigned short)a2[j]) + bf2f((unsigned short)a3[j]);
        out[base + j] = s + bias[col + j] + resid[base + j];
    }
}

// ---------------- Flash attention (causal), split-KV across blocks ------------
// FINER GRANULARITY: block = 2 waves x 64 q-rows (qb in 0..31), chunk = 8 KV
// tiles. Grid 80 x 24 = 1920 blocks, max weight 8 tiles -> halved per-CU load
// variance (makespan was tail-bound; all blocks co-resident).
// K staged in LDS (XOR-swizzled dbuf gload_lds); V direct from global.
// No-max softmax; q pre-scaled by log2e/8; truncating bf16 P-staging.
__global__ __launch_bounds__(128) void attn_kernel(const unsigned short* __restrict__ q_s,
                                                   const unsigned short* __restrict__ k_s,
                                                   const unsigned short* __restrict__ v_t,
                                                   unsigned short* __restrict__ y,
                                                   unsigned short* __restrict__ opart,
                                                   float* __restrict__ lpart) {
    __shared__ unsigned short KVs[2][4096];   // K tile 64x64 bf16, double-buffered
    __shared__ unsigned short Pls[2][32][72]; // per-wave P staging
    const int T = 2048, H = 12;
    int tid = threadIdx.x, lane = tid & 63, w = tid >> 6;   // w in {0,1}
    // decode blockIdx.x -> (qb, c): qb has qb+1 KV tiles, chunks of 8
    int xx = (int)blockIdx.x;
    int qb, c;
    if (xx < 32)      { c = 0; qb = xx; }
    else if (xx < 56) { c = 1; qb = xx - 24; }
    else if (xx < 72) { c = 2; qb = xx - 40; }
    else              { c = 3; qb = xx - 48; }
    int bh = blockIdx.y;
    int bi = bh / H, hh = bh - bi * H;
    const unsigned short* qp = q_s + (size_t)bh * T * 64;
    const unsigned short* kp = k_s + (size_t)bh * T * 64;
    const unsigned short* vp = v_t + (size_t)bh * 64 * T;
    int wq0 = qb * 64 + w * 32;
    int lr = lane & 15, lk8 = (lane >> 4) << 3, hi = lane >> 4;
    int nt_blk = qb + 1;
    int t0 = c * 8;
    int t1 = t0 + 8 < nt_blk ? t0 + 8 : nt_blk;

    unsigned short (*Pl)[72] = Pls[w];

    auto stage = [&](int buf, int t) {
        int kv0 = t * 64;
        unsigned short* base = &KVs[buf][w * 512];
#pragma unroll
        for (int h = 0; h < 4; h++) {
            int r = w * 8 + h * 16 + (lane >> 3);
            int ss = (lane & 7) ^ (r & 7);
            gload16(kp + (size_t)(kv0 + r) * 64 + ss * 8, base + h * 1024);
        }
    };

    short8 aq[2][2];
#pragma unroll
    for (int mt = 0; mt < 2; mt++)
#pragma unroll
        for (int kf = 0; kf < 2; kf++)
            aq[mt][kf] = *(const short8*)&qp[(size_t)(wq0 + mt * 16 + lr) * 64 + kf * 32 + lk8];

    floatx4 yacc[2][4];
    float lacc[2][4];
#pragma unroll
    for (int i = 0; i < 2; i++)
#pragma unroll
        for (int j = 0; j < 4; j++) {
            yacc[i][j] = (floatx4){0.f, 0.f, 0.f, 0.f};
            lacc[i][j] = 0.f;
        }

    stage(0, t0);
    __syncthreads();

    for (int t = t0; t < t1; t++) {
        int cur = (t - t0) & 1;
        if (t + 1 < t1) stage(cur ^ 1, t + 1);
        int kv0 = t * 64;
        if (kv0 <= wq0 + 31) {
            const unsigned short* Kt = &KVs[cur][0];
            floatx4 sacc[2][4];
#pragma unroll
            for (int i = 0; i < 2; i++)
#pragma unroll
                for (int j = 0; j < 4; j++) sacc[i][j] = (floatx4){0.f, 0.f, 0.f, 0.f};
#pragma unroll
            for (int kf = 0; kf < 2; kf++) {
                int sl = ((kf << 2) | hi) ^ (lr & 7);
                short8 bk[4];
#pragma unroll
                for (int nt = 0; nt < 4; nt++)
                    bk[nt] = *(const short8*)&Kt[(nt * 16 + lr) * 64 + sl * 8];
#pragma unroll
                for (int mt = 0; mt < 2; mt++)
#pragma unroll
                    for (int nt = 0; nt < 4; nt++)
                        sacc[mt][nt] = __builtin_amdgcn_mfma_f32_16x16x32_bf16(aq[mt][kf], bk[nt], sacc[mt][nt], 0, 0, 0);
            }
            // V direct from global; issued early, consumed after softmax
            short8 bv[4][2];
#pragma unroll
            for (int nt = 0; nt < 4; nt++)
#pragma unroll
                for (int kf = 0; kf < 2; kf++)
                    bv[nt][kf] = *(const short8*)&vp[(size_t)(nt * 16 + lr) * T + kv0 + kf * 32 + lk8];
            bool full = (kv0 + 63 <= wq0);
#pragma unroll
            for (int mt = 0; mt < 2; mt++)
#pragma unroll
                for (int r = 0; r < 4; r++) {
                    int qg = wq0 + mt * 16 + (hi << 2) + r;
                    int prow = mt * 16 + (hi << 2) + r;
#pragma unroll
                    for (int nt = 0; nt < 4; nt++) {
                        float sv = sacc[mt][nt][r];
                        if (!full) {
                            int kvg = kv0 + nt * 16 + lr;
                            sv = (kvg <= qg) ? sv : -1e30f;
                        }
                        float p = fexp2(sv);
                        lacc[mt][r] += p;
                        Pl[prow][nt * 16 + lr] = f2bf_t(p);
                    }
                }
            // PV
#pragma unroll
            for (int kf = 0; kf < 2; kf++) {
                short8 pa[2];
#pragma unroll
                for (int mt = 0; mt < 2; mt++) pa[mt] = *(short8*)&Pl[mt * 16 + lr][kf * 32 + lk8];
#pragma unroll
                for (int mt = 0; mt < 2; mt++)
#pragma unroll
                    for (int nt = 0; nt < 4; nt++)
                        yacc[mt][nt] = __builtin_amdgcn_mfma_f32_16x16x32_bf16(pa[mt], bv[nt][kf], yacc[mt][nt], 0, 0, 0);
            }
        }
        __syncthreads();
    }

    if (nt_blk <= 8) {   // single chunk (qb < 8): normalize, write y directly
#pragma unroll
        for (int mt = 0; mt < 2; mt++)
#pragma unroll
            for (int r = 0; r < 4; r++) {
                float l = lacc[mt][r];
                l += __shfl_xor(l, 1);
                l += __shfl_xor(l, 2);
                l += __shfl_xor(l, 4);
                l += __shfl_xor(l, 8);
                float inv = 1.f / l;
                int qg = wq0 + mt * 16 + (hi << 2) + r;
#pragma unroll
                for (int nt = 0; nt < 4; nt++)
                    y[((size_t)(bi * T + qg)) * 768 + hh * 64 + nt * 16 + lr] = f2bf(yacc[mt][nt][r] * inv);
            }
    } else {
        // slab index: chunks before qb (qb>=8), minus the 8 direct blocks
        int base = (qb <= 15) ? (qb - 8) * 2
                 : (qb <= 23) ? 16 + (qb - 16) * 3
                              : 40 + (qb - 24) * 4;
        int slab = bh * 72 + base + c;
        unsigned short* op = opart + (size_t)slab * 4096;
        float* lp = lpart + (size_t)slab * 64;
#pragma unroll
        for (int mt = 0; mt < 2; mt++)
#pragma unroll
            for (int r = 0; r < 4; r++) {
                float l = lacc[mt][r];
                l += __shfl_xor(l, 1);
                l += __shfl_xor(l, 2);
                l += __shfl_xor(l, 4);
                l += __shfl_xor(l, 8);
                int wrow = w * 32 + mt * 16 + (hi << 2) + r;
                if (lr == 0) lp[wrow] = l;
#pragma unroll
                for (int nt = 0; nt < 4; nt++)
                    op[(size_t)wrow * 64 + nt * 16 + lr] = f2bf(yacc[mt][nt][r]);
            }
    }
}

// ---------------- Combine split-KV partials: sum, normalize, write y ----------
// qb in 8..31 (grid.x = 24), 64-row slabs.
__global__ __launch_bounds__(256) void attn_combine(const unsigned short* __restrict__ opart,
                                                    const float* __restrict__ lpart,
                                                    unsigned short* __restrict__ y) {
    const int T = 2048, H = 12;
    int qb = 8 + (int)blockIdx.x;
    int bh = blockIdx.y;
    int bi = bh / H, hh = bh - bi * H;
    int nchunk = (qb <= 15) ? 2 : (qb <= 23) ? 3 : 4;
    int base = (qb <= 15) ? (qb - 8) * 2
             : (qb <= 23) ? 16 + (qb - 16) * 3
                          : 40 + (qb - 24) * 4;
    int tid = threadIdx.x;
    int row = tid >> 2, cb = (tid & 3) * 16;

    float l = 0.f;
    for (int c = 0; c < nchunk; c++) l += lpart[(size_t)(bh * 72 + base + c) * 64 + row];
    float inv = 1.f / l;

    float s[16];
#pragma unroll
    for (int j = 0; j < 16; j++) s[j] = 0.f;
    for (int c = 0; c < nchunk; c++) {
        const unsigned short* op = opart + ((size_t)(bh * 72 + base + c) * 64 + row) * 64 + cb;
#pragma unroll
        for (int v = 0; v < 2; v++) {
            short8 ob = *(const short8*)&op[v * 8];
#pragma unroll
            for (int j = 0; j < 8; j++) s[v * 8 + j] += bf2f((unsigned short)ob[j]);
        }
    }
    int qg = qb * 64 + row;
    unsigned short* yr = y + ((size_t)(bi * T + qg)) * 768 + hh * 64 + cb;
#pragma unroll
    for (int v = 0; v < 2; v++) {
        short8 ob;
#pragma unroll
        for (int j = 0; j < 8; j++) ob[j] = (short)f2bf(s[v * 8 + j] * inv);
        *(short8*)&yr[v * 8] = ob;
    }
}

extern "C" void kernel_launch(void* const* d_in, const int* in_sizes, int n_in,
                              void* d_out, int out_size, void* d_ws, size_t ws_size,
                              hipStream_t stream) {
    const float* x    = (const float*)d_in[0];
    const float* ln1w = (const float*)d_in[1];
    const float* ln1b = (const float*)d_in[2];
    const float* wqkv = (const float*)d_in[3];
    const float* bqkv = (const float*)d_in[4];
    const float* wproj= (const float*)d_in[5];
    const float* bproj= (const float*)d_in[6];
    const float* ln2w = (const float*)d_in[7];
    const float* ln2b = (const float*)d_in[8];
    const float* wfc1 = (const float*)d_in[9];
    const float* bfc1 = (const float*)d_in[10];
    const float* wfc2 = (const float*)d_in[11];
    const float* bfc2 = (const float*)d_in[12];
    float* out = (float*)d_out;

    char* ws = (char*)d_ws;
    size_t off = 0;
    auto alloc = [&](size_t bytes) { void* p = ws + off; off += (bytes + 255) & ~(size_t)255; return p; };

    const size_t MT = 4096;  // tokens
    unsigned short* wqkv_t = (unsigned short*)alloc(2304 * 768 * 2);
    unsigned short* wproj_t= (unsigned short*)alloc(768 * 768 * 2);
    unsigned short* wfc1_t = (unsigned short*)alloc(3072 * 768 * 2);
    unsigned short* wfc2_t = (unsigned short*)alloc(768 * 3072 * 2);
    unsigned short* h12    = (unsigned short*)alloc(MT * 768 * 2);
    float*          x1     = (float*)alloc(MT * 768 * 4);
    unsigned short* qs     = (unsigned short*)alloc(MT * 768 * 2);
    unsigned short* ks     = (unsigned short*)alloc(MT * 768 * 2);
    unsigned short* vt     = (unsigned short*)alloc(MT * 768 * 2);
    unsigned short* yb     = (unsigned short*)alloc(MT * 768 * 2);
    unsigned short* hm     = qs;  // [4096,3072] bf16 aliases qs..yb (exactly 4x)
    unsigned short* opart  = (unsigned short*)alloc((size_t)24 * 72 * 4096 * 2);  // 14.2 MB
    float*          lpart  = (float*)alloc((size_t)24 * 72 * 64 * 4);             // 0.44 MB

    // fc2 split-K partials alias dead regions at fc2 time
    unsigned short* p0 = (unsigned short*)ws;
    unsigned short* p1 = opart;
    unsigned short* p2 = (unsigned short*)((char*)opart + (size_t)MT * 768 * 2);
    unsigned short* p3 = h12;

    wt_all_kernel<<<dim3(6912), 256, 0, stream>>>(wqkv, wqkv_t, wproj, wproj_t,
                                                  wfc1, wfc1_t, wfc2, wfc2_t);

    ln_kernel<<<4096, 256, 0, stream>>>(x, ln1w, ln1b, h12);
    gemm_kernel<0><<<dim3(18, 32), 256, 0, stream>>>(h12, wqkv_t, bqkv, nullptr, nullptr, qs, ks, vt, 768, 768);
    attn_kernel<<<dim3(80, 24), 128, 0, stream>>>(qs, ks, vt, yb, opart, lpart);
    attn_combine<<<dim3(24, 24), 256, 0, stream>>>(opart, lpart, yb);
    gemm_kernel<1><<<dim3(6, 32), 256, 0, stream>>>(yb, wproj_t, bproj, x, x1, nullptr, nullptr, nullptr, 768, 768);
    ln_kernel<<<4096, 256, 0, stream>>>(x1, ln2w, ln2b, h12);
    gemm_kernel<2><<<dim3(24, 32), 256, 0, stream>>>(h12, wfc1_t, bfc1, nullptr, nullptr, hm, nullptr, nullptr, 768, 768);
    gemm_kernel<4><<<dim3(24, 32), 256, 0, stream>>>(hm, wfc2_t, nullptr, nullptr, (float*)p3, p0, p1, p2, 3072, 768);
    sk_combine<<<dim3(1536), 256, 0, stream>>>(p0, p1, p2, p3, bfc2, x1, out);
}